// Round 5
// baseline (293.601 us; speedup 1.0000x reference)
//
#include <hip/hip_runtime.h>

// SnConv3: B=8, N=32, C=64, O=64
#define NBATCH 8
#define NN 32
#define NC 64
#define NO 64
#define C6 384
#define C10 640
#define C12 768
#define C5 320

typedef __attribute__((ext_vector_type(8))) short short8;   // 8 bf16 (4 VGPRs)
typedef __attribute__((ext_vector_type(4))) float float4v;  // 4 fp32

// workspace layout (float offsets)
static constexpr int OFF_ABF = 0;        // a2 bf16 [8][32][32][384] = 1,572,864 floats
static constexpr int OFF_A1  = 1572864;  // [8][32][640] f32        =   163,840
static constexpr int OFF_A0  = 1736704;  // [8][320] f32            =     2,560
static constexpr int OFF_R1  = 1739264;  // [3][8][32][64]          =    49,152
static constexpr int OFF_R1T = 1788416;  // [3][8][32][64]          =    49,152
static constexpr int OFF_R0  = 1837568;  // [3][8][64]              =     1,536
static constexpr int OFF_MD  = 1839104;  // [8][32][64]             =    16,384
static constexpr int OFF_WB  = 1855488;  // W33 bf16 frags: 24576 sh =   12,288
static constexpr int OFF_WB2 = 1867776;  // W22 bf16 frags: 147456 sh=   73,728
// total 1,941,504 floats ~= 7.8 MB

__device__ __forceinline__ unsigned short f2bf(float f) {
    union { float f; unsigned u; } x{f};
    unsigned r = x.u + 0x7fffu + ((x.u >> 16) & 1u);  // RNE
    return (unsigned short)(r >> 16);
}

__device__ __forceinline__ void store_bf4(unsigned short* p, float4v v) {
    ushort4 w;
    w.x = f2bf(v.x); w.y = f2bf(v.y); w.z = f2bf(v.z); w.w = f2bf(v.w);
    *(ushort4*)p = w;
}

__device__ __forceinline__ float4v bf4(const unsigned short* p) {
    ushort4 u = *(const ushort4*)(p);
    float4v r;
    r.x = __uint_as_float((unsigned)u.x << 16);
    r.y = __uint_as_float((unsigned)u.y << 16);
    r.z = __uint_as_float((unsigned)u.z << 16);
    r.w = __uint_as_float((unsigned)u.w << 16);
    return r;
}

// ---------------------------------------------------------------------------
// K0: weight prep. W33 [384][64] and W22 [3][768][64] f32 -> bf16 B-fragments
// ---------------------------------------------------------------------------
__global__ __launch_bounds__(256) void k_prepw(const float* __restrict__ W33,
                                               const float* __restrict__ W22,
                                               float* __restrict__ ws) {
    int id = blockIdx.x * 256 + threadIdx.x;  // 21504
    if (id < 3072) {                          // W33: nt(4) x ks(12) x lane(64)
        int lane = id & 63;
        int ks = (id >> 6) % 12;
        int nt = (id >> 6) / 12;
        int n = nt * 16 + (lane & 15);
        int k0 = ks * 32 + (lane >> 4) * 8;
        unsigned short* dst = (unsigned short*)(ws + OFF_WB) +
                              (size_t)((nt * 12 + ks) * 64 + lane) * 8;
#pragma unroll
        for (int jj = 0; jj < 8; ++jj) dst[jj] = f2bf(W33[(k0 + jj) * 64 + n]);
    } else if (id < 21504) {                  // W22: i(3) x nt(4) x ks(24) x lane(64)
        int q = id - 3072;
        int lane = q & 63;
        int ks = (q >> 6) % 24;
        int r = (q >> 6) / 24;
        int nt = r & 3;
        int i = r >> 2;
        int n = nt * 16 + (lane & 15);
        int k0 = ks * 32 + (lane >> 4) * 8;
        const float* W = W22 + (size_t)i * C12 * NO;
        unsigned short* dst = (unsigned short*)(ws + OFF_WB2) +
                              (size_t)(((i * 4 + nt) * 24 + ks) * 64 + lane) * 8;
#pragma unroll
        for (int jj = 0; jj < 8; ++jj) dst[jj] = f2bf(W[(k0 + jj) * 64 + n]);
    }
}

// ---------------------------------------------------------------------------
// K1: a2 (bf16): s1,s2,s3 (axis means) + d12,d13,d23 (diagonals)
// ---------------------------------------------------------------------------
__global__ __launch_bounds__(256) void k_contract2(const float* __restrict__ x,
                                                   float* __restrict__ ws) {
    int id = blockIdx.x * 256 + threadIdx.x;
    int c4 = id & 15;
    int v = (id >> 4) & 31;
    int u = (id >> 9) & 31;
    int b = id >> 14;
    int bc = c4 * 4;
    const float* xb = x + (size_t)b * 2097152;

    float4v s1 = {0.f, 0.f, 0.f, 0.f}, s2 = s1, s3 = s1;
    {
        const float* p = xb + u * 2048 + v * 64 + bc;
        for (int i = 0; i < 32; ++i) s1 += *(const float4v*)(p + i * 65536);
    }
    {
        const float* p = xb + u * 65536 + v * 64 + bc;
        for (int j = 0; j < 32; ++j) s2 += *(const float4v*)(p + j * 2048);
    }
    {
        const float* p = xb + u * 65536 + v * 2048 + bc;
        for (int k = 0; k < 32; ++k) s3 += *(const float4v*)(p + k * 64);
    }
    float4v d12 = *(const float4v*)(xb + v * 65536 + v * 2048 + u * 64 + bc);
    float4v d13 = *(const float4v*)(xb + v * 65536 + u * 2048 + v * 64 + bc);
    float4v d23 = *(const float4v*)(xb + u * 65536 + v * 2048 + v * 64 + bc);

    const float inv = 1.0f / 32.0f;
    unsigned short* a2 = (unsigned short*)(ws + OFF_ABF) +
                         (size_t)((b * 32 + u) * 32 + v) * C6 + bc;
    store_bf4(a2 + 0 * 64, s1 * inv);
    store_bf4(a2 + 1 * 64, s2 * inv);
    store_bf4(a2 + 2 * 64, s3 * inv);
    store_bf4(a2 + 3 * 64, d12);
    store_bf4(a2 + 4 * 64, d13);
    store_bf4(a2 + 5 * 64, d23);
}

// ---------------------------------------------------------------------------
// K2: a1 from bf16 a2 + triple diagonal. Block per (b,t), 16-way split + LDS.
// thread (g=tid>>4, c4=tid&15): rows u,v in {2g,2g+1}; 9 float4 partials.
// ---------------------------------------------------------------------------
__global__ __launch_bounds__(256) void k_contract1(const float* __restrict__ x,
                                                   float* __restrict__ ws) {
    __shared__ float4v P[9][16][16];  // [chunk][g][c4]
    int blk = blockIdx.x;  // b*32 + t
    int b = blk >> 5;
    int t = blk & 31;
    int tid = threadIdx.x;
    int g = tid >> 4;
    int c4 = tid & 15;
    int bc = c4 * 4;
    const unsigned short* a2 = (const unsigned short*)(ws + OFF_ABF) +
                               (size_t)b * 32 * 32 * C6;

    float4v p0 = {0.f,0.f,0.f,0.f}, p1 = p0, p2 = p0, p3 = p0, p4 = p0,
            p5 = p0, p6 = p0, p7 = p0, p8 = p0;
#pragma unroll
    for (int w = 0; w < 2; ++w) {
        int u = 2 * g + w;
        const unsigned short* rowu = a2 + (size_t)(u * 32 + t) * C6 + bc;
        p0 += bf4(rowu + 0);    // su0
        p3 += bf4(rowu + 192);  // su3
        p5 += bf4(rowu + 256);  // su4
        p7 += bf4(rowu + 320);  // su5
        const unsigned short* rowv = a2 + (size_t)(t * 32 + u) * C6 + bc;
        p1 += bf4(rowv + 0);    // sv0
        p2 += bf4(rowv + 64);   // sv1
        p4 += bf4(rowv + 192);  // sv3
        p6 += bf4(rowv + 256);  // sv4
        p8 += bf4(rowv + 320);  // sv5
    }
    P[0][g][c4] = p0; P[1][g][c4] = p1; P[2][g][c4] = p2;
    P[3][g][c4] = p3; P[4][g][c4] = p4; P[5][g][c4] = p5;
    P[6][g][c4] = p6; P[7][g][c4] = p7; P[8][g][c4] = p8;
    __syncthreads();

    float* a1 = ws + OFF_A1 + ((size_t)b * 32 + t) * C10;
    if (tid < 144) {
        int p = tid >> 4;
        int cc = tid & 15;
        float4v s = {0.f,0.f,0.f,0.f};
#pragma unroll
        for (int gg = 0; gg < 16; ++gg) s += P[p][gg][cc];
        *(float4v*)(a1 + p * 64 + cc * 4) = s * (1.0f / 32.0f);
    } else if (tid < 160) {
        int cc = tid - 144;
        float4v td = *(const float4v*)(x + (((size_t)b * 32 + t) * 32 + t) * 2048 + t * 64 + cc * 4);
        *(float4v*)(a1 + 9 * 64 + cc * 4) = td;
    }
}

// ---------------------------------------------------------------------------
// K3: a0 (5 chunks of C) from a1.
// ---------------------------------------------------------------------------
__global__ __launch_bounds__(256) void k_contract0(float* __restrict__ ws) {
    int id = blockIdx.x * 256 + threadIdx.x;
    if (id >= 512) return;
    int c = id & 63;
    int b = id >> 6;
    const float* a1 = ws + OFF_A1 + (size_t)b * 32 * C10;
    float s0 = 0, s1 = 0, s2 = 0, s3 = 0, s4 = 0;
    for (int t = 0; t < 32; ++t) {
        const float* row = a1 + t * C10;
        s0 += row[0 * 64 + c];
        s1 += row[3 * 64 + c];
        s2 += row[5 * 64 + c];
        s3 += row[7 * 64 + c];
        s4 += row[9 * 64 + c];
    }
    float* a0 = ws + OFF_A0 + b * C5;
    const float inv = 1.0f / 32.0f;
    a0[0 * 64 + c] = s0 * inv;
    a0[1 * 64 + c] = s1 * inv;
    a0[2 * 64 + c] = s2 * inv;
    a0[3 * 64 + c] = s3 * inv;
    a0[4 * 64 + c] = s4 * inv;
}

// ---------------------------------------------------------------------------
// K4: row GEMVs. Blocks 0..255 = (b,t): r1[0..2], r1t[0..2], mdiag with 4-way
// K-split + LDS reduce (a1 loads are wave-uniform -> scalarized). Block 256: r0.
// ---------------------------------------------------------------------------
__global__ __launch_bounds__(256) void k_rowmix(
    const float* __restrict__ W12, const float* __restrict__ b12,
    const float* __restrict__ W12t, const float* __restrict__ b12t,
    const float* __restrict__ W02, const float* __restrict__ b02,
    const float* __restrict__ W11, const float* __restrict__ b11,
    const float* __restrict__ W01, const float* __restrict__ b01,
    float* __restrict__ ws) {
    int blk = blockIdx.x;
    int tid = threadIdx.x;
    if (blk < 256) {
        __shared__ float P2[7][4][64];  // [kind][g][o]
        int b = blk >> 5;
        int t = blk & 31;
        int o = tid & 63;
        int g = tid >> 6;
        const float* a1 = ws + OFF_A1 + ((size_t)b * 32 + t) * C10;
        const float* a0 = ws + OFF_A0 + (size_t)b * C5;
        float acc[7] = {0.f, 0.f, 0.f, 0.f, 0.f, 0.f, 0.f};
        for (int m = g * 160; m < g * 160 + 160; ++m) {
            float a = a1[m];
            acc[0] += a * W12 [(size_t)0 * C10 * NO + m * NO + o];
            acc[1] += a * W12 [(size_t)1 * C10 * NO + m * NO + o];
            acc[2] += a * W12 [(size_t)2 * C10 * NO + m * NO + o];
            acc[3] += a * W12t[(size_t)0 * C10 * NO + m * NO + o];
            acc[4] += a * W12t[(size_t)1 * C10 * NO + m * NO + o];
            acc[5] += a * W12t[(size_t)2 * C10 * NO + m * NO + o];
            acc[6] += a * W11 [m * NO + o];
        }
        for (int m = g * 80; m < g * 80 + 80; ++m)
            acc[6] += a0[m] * W01[m * NO + o];
#pragma unroll
        for (int kk = 0; kk < 7; ++kk) P2[kk][g][o] = acc[kk];
        __syncthreads();
        for (int out = tid; out < 448; out += 256) {
            int kind = out >> 6;
            int oo = out & 63;
            float s = P2[kind][0][oo] + P2[kind][1][oo] + P2[kind][2][oo] + P2[kind][3][oo];
            if (kind < 3) {
                s += b12[kind * NO + oo];
                ws[OFF_R1 + (((size_t)kind * 8 + b) * 32 + t) * NO + oo] = s;
            } else if (kind < 6) {
                int i = kind - 3;
                s += b12t[i * NO + oo];
                ws[OFF_R1T + (((size_t)i * 8 + b) * 32 + t) * NO + oo] = s;
            } else {
                s += b11[oo] + b01[oo];
                ws[OFF_MD + ((size_t)b * 32 + t) * NO + oo] = s;
            }
        }
    } else {  // r0: 1536 outputs
        for (int idx = tid; idx < 1536; idx += 256) {
            int i = idx >> 9;
            int b = (idx >> 6) & 7;
            int o = idx & 63;
            const float* a0 = ws + OFF_A0 + (size_t)b * C5;
            float acc = b02[i * NO + o];
            for (int m = 0; m < C5; ++m)
                acc += a0[m] * W02[(size_t)i * C5 * NO + m * NO + o];
            ws[OFF_R0 + ((size_t)i * 8 + b) * NO + o] = acc;
        }
    }
}

// ---------------------------------------------------------------------------
// K5 (main, MFMA, pipelined): block handles 4 j-contiguous tiles of (b,i).
// Prefetch next tile's 12 float4 into registers during current tile's MFMA.
// ---------------------------------------------------------------------------
__global__ __launch_bounds__(256) void k_main(const float* __restrict__ x,
                                              const float* __restrict__ ws,
                                              const float* __restrict__ b33,
                                              float* __restrict__ T) {
    __shared__ __align__(16) unsigned short As[32 * 392];  // 392 = 384 + 8 pad
    int tid = threadIdx.x;
    const unsigned short* WB = (const unsigned short*)(ws + OFF_WB);

    int wv = tid >> 6;
    int lane = tid & 63;
    int m_tile = wv & 1;
    int n_pair = wv >> 1;
    int colq = lane & 15;
    int quad = lane >> 4;

    // B fragments once per block
    short8 bfr[2][12];
#pragma unroll
    for (int np = 0; np < 2; ++np) {
        int nt = n_pair * 2 + np;
#pragma unroll
        for (int ks = 0; ks < 12; ++ks)
            bfr[np][ks] = *(const short8*)(WB + (size_t)((nt * 12 + ks) * 64 + lane) * 8);
    }
    float bb0 = b33[(n_pair * 2 + 0) * 16 + colq];
    float bb1 = b33[(n_pair * 2 + 1) * 16 + colq];

    int blk = blockIdx.x;           // b(3) | i(5) | jg(3)
    int b = blk >> 8;
    int i = (blk >> 3) & 31;
    int jg = blk & 7;
    const float* xb = x + (size_t)b * 2097152;

    int k0 = wv * 8;
    int c = colq * 4;
    int kA = k0 + quad;
    int kB = k0 + quad + 4;
    int mrow = m_tile * 16 + colq;
    const unsigned short* Arow = &As[mrow * 392 + quad * 8];

    auto load_tile = [&](int j, float4v* pf) {
        pf[0]  = *(const float4v*)(xb + i * 65536 + j * 2048 + kA * 64 + c);
        pf[1]  = *(const float4v*)(xb + i * 65536 + kA * 2048 + j * 64 + c);
        pf[2]  = *(const float4v*)(xb + j * 65536 + i * 2048 + kA * 64 + c);
        pf[3]  = *(const float4v*)(xb + kA * 65536 + i * 2048 + j * 64 + c);
        pf[4]  = *(const float4v*)(xb + j * 65536 + kA * 2048 + i * 64 + c);
        pf[5]  = *(const float4v*)(xb + kA * 65536 + j * 2048 + i * 64 + c);
        pf[6]  = *(const float4v*)(xb + i * 65536 + j * 2048 + kB * 64 + c);
        pf[7]  = *(const float4v*)(xb + i * 65536 + kB * 2048 + j * 64 + c);
        pf[8]  = *(const float4v*)(xb + j * 65536 + i * 2048 + kB * 64 + c);
        pf[9]  = *(const float4v*)(xb + kB * 65536 + i * 2048 + j * 64 + c);
        pf[10] = *(const float4v*)(xb + j * 65536 + kB * 2048 + i * 64 + c);
        pf[11] = *(const float4v*)(xb + kB * 65536 + j * 2048 + i * 64 + c);
    };

    float4v pf[12];
    load_tile(jg * 4, pf);

#pragma unroll
    for (int s = 0; s < 4; ++s) {
        int j = jg * 4 + s;
        // write current tile to LDS
        unsigned short* dA = &As[kA * 392 + c];
        store_bf4(dA + 0 * 64, pf[0]);
        store_bf4(dA + 1 * 64, pf[1]);
        store_bf4(dA + 2 * 64, pf[2]);
        store_bf4(dA + 3 * 64, pf[3]);
        store_bf4(dA + 4 * 64, pf[4]);
        store_bf4(dA + 5 * 64, pf[5]);
        unsigned short* dB = &As[kB * 392 + c];
        store_bf4(dB + 0 * 64, pf[6]);
        store_bf4(dB + 1 * 64, pf[7]);
        store_bf4(dB + 2 * 64, pf[8]);
        store_bf4(dB + 3 * 64, pf[9]);
        store_bf4(dB + 4 * 64, pf[10]);
        store_bf4(dB + 5 * 64, pf[11]);
        __syncthreads();

        float4v nf[12];
        if (s < 3) load_tile(j + 1, nf);  // overlap with MFMA below

        float4v acc0 = {0.f, 0.f, 0.f, 0.f};
        float4v acc1 = {0.f, 0.f, 0.f, 0.f};
#pragma unroll
        for (int ks = 0; ks < 12; ++ks) {
            short8 a = *(const short8*)(Arow + ks * 32);
            acc0 = __builtin_amdgcn_mfma_f32_16x16x32_bf16(a, bfr[0][ks], acc0, 0, 0, 0);
            acc1 = __builtin_amdgcn_mfma_f32_16x16x32_bf16(a, bfr[1][ks], acc1, 0, 0, 0);
        }

        float* Tb = T + ((size_t)(b * 1024 + i * 32 + j)) * 2048;
#pragma unroll
        for (int r = 0; r < 4; ++r) {
            int m = m_tile * 16 + quad * 4 + r;
            int o0 = (n_pair * 2 + 0) * 16 + colq;
            int o1 = (n_pair * 2 + 1) * 16 + colq;
            __builtin_nontemporal_store(acc0[r] + bb0, &Tb[m * 64 + o0]);
            __builtin_nontemporal_store(acc1[r] + bb1, &Tb[m * 64 + o1]);
        }
        __syncthreads();
        if (s < 3) {
#pragma unroll
            for (int q = 0; q < 12; ++q) pf[q] = nf[q];
        }
    }
}

// ---------------------------------------------------------------------------
// K6 (slices, MFMA, fused expand): block per (b,t).
// ---------------------------------------------------------------------------
__global__ __launch_bounds__(256) void k_slices(const float* __restrict__ b22,
                                                float* __restrict__ T,
                                                const float* __restrict__ ws) {
    __shared__ __align__(16) unsigned short As[32 * 776];  // 776 = 768 + 8 pad
    int blk = blockIdx.x;  // b*32 + t
    int b = blk >> 5;
    int t = blk & 31;
    int tid = threadIdx.x;
    const unsigned short* abf = (const unsigned short*)(ws + OFF_ABF);
    const unsigned short* WB2 = (const unsigned short*)(ws + OFF_WB2);

    for (int l = tid; l < 3072; l += 256) {
        int d = l / 96;
        int m8 = l - d * 96;
        const unsigned short* src = (m8 < 48)
            ? abf + (size_t)(((b * 32 + t) * 32 + d) * C6) + m8 * 8
            : abf + (size_t)(((b * 32 + d) * 32 + t) * C6) + (m8 - 48) * 8;
        *(short8*)&As[d * 776 + m8 * 8] = *(const short8*)src;
    }
    __syncthreads();

    int wv = tid >> 6;
    int lane = tid & 63;
    int mt = wv & 1;
    int nh = wv >> 1;
    float4v zero = {0.f, 0.f, 0.f, 0.f};
    float4v acc[3][2] = {{zero, zero}, {zero, zero}, {zero, zero}};
    const unsigned short* Arow = &As[(mt * 16 + (lane & 15)) * 776 + (lane >> 4) * 8];
#pragma unroll
    for (int ks = 0; ks < 24; ++ks) {
        short8 a = *(const short8*)(Arow + ks * 32);
#pragma unroll
        for (int i = 0; i < 3; ++i) {
#pragma unroll
            for (int np = 0; np < 2; ++np) {
                int nt = nh * 2 + np;
                short8 bf = *(const short8*)(WB2 + (size_t)(((i * 4 + nt) * 24 + ks) * 64 + lane) * 8);
                acc[i][np] = __builtin_amdgcn_mfma_f32_16x16x32_bf16(a, bf, acc[i][np], 0, 0, 0);
            }
        }
    }

    int colq = lane & 15;
    int quad = lane >> 4;
    float* Tb = T + (size_t)b * 2097152;
#pragma unroll
    for (int np = 0; np < 2; ++np) {
        int o = (nh * 2 + np) * 16 + colq;
        float base0 = b22[0 * 64 + o] + ws[OFF_R1 + ((size_t)(0 * 8 + b) * 32 + t) * 64 + o]
                    + ws[OFF_R0 + (size_t)(0 * 8 + b) * 64 + o];
        float base1 = b22[1 * 64 + o] + ws[OFF_R1 + ((size_t)(1 * 8 + b) * 32 + t) * 64 + o]
                    + ws[OFF_R0 + (size_t)(1 * 8 + b) * 64 + o];
        float base2 = b22[2 * 64 + o] + ws[OFF_R1 + ((size_t)(2 * 8 + b) * 32 + t) * 64 + o]
                    + ws[OFF_R0 + (size_t)(2 * 8 + b) * 64 + o];
#pragma unroll
        for (int r = 0; r < 4; ++r) {
            int d = mt * 16 + quad * 4 + r;
            float s0 = acc[0][np][r] + base0 + ws[OFF_R1T + ((size_t)(0 * 8 + b) * 32 + d) * 64 + o];
            float s1 = acc[1][np][r] + base1 + ws[OFF_R1T + ((size_t)(1 * 8 + b) * 32 + d) * 64 + o];
            float s2 = acc[2][np][r] + base2 + ws[OFF_R1T + ((size_t)(2 * 8 + b) * 32 + d) * 64 + o];
            if (d != t) {
                Tb[d * 65536 + d * 2048 + t * 64 + o] += s0;
                Tb[d * 65536 + t * 2048 + d * 64 + o] += s1;
                Tb[t * 65536 + d * 2048 + d * 64 + o] += s2;
            } else {
                float md = ws[OFF_MD + ((size_t)b * 32 + d) * 64 + o];
                Tb[d * 65536 + d * 2048 + d * 64 + o] += s0 + s1 + s2 + md;
            }
        }
    }
}

// ---------------------------------------------------------------------------
extern "C" void kernel_launch(void* const* d_in, const int* in_sizes, int n_in,
                              void* d_out, int out_size, void* d_ws, size_t ws_size,
                              hipStream_t stream) {
    const float* x    = (const float*)d_in[0];
    const float* W33  = (const float*)d_in[1];
    const float* b33  = (const float*)d_in[2];
    const float* W22  = (const float*)d_in[3];
    const float* b22  = (const float*)d_in[4];
    const float* W12  = (const float*)d_in[5];
    const float* b12  = (const float*)d_in[6];
    const float* W12t = (const float*)d_in[7];
    const float* b12t = (const float*)d_in[8];
    const float* W02  = (const float*)d_in[9];
    const float* b02  = (const float*)d_in[10];
    const float* W11  = (const float*)d_in[11];
    const float* b11  = (const float*)d_in[12];
    const float* W01  = (const float*)d_in[13];
    const float* b01  = (const float*)d_in[14];
    float* T  = (float*)d_out;
    float* ws = (float*)d_ws;

    hipLaunchKernelGGL(k_prepw, dim3(84), dim3(256), 0, stream, W33, W22, ws);
    hipLaunchKernelGGL(k_contract2, dim3(512), dim3(256), 0, stream, x, ws);
    hipLaunchKernelGGL(k_contract1, dim3(256), dim3(256), 0, stream, x, ws);
    hipLaunchKernelGGL(k_contract0, dim3(2), dim3(256), 0, stream, ws);
    hipLaunchKernelGGL(k_rowmix, dim3(257), dim3(256), 0, stream,
                       W12, b12, W12t, b12t, W02, b02, W11, b11, W01, b01, ws);
    hipLaunchKernelGGL(k_main, dim3(2048), dim3(256), 0, stream, x, ws, b33, T);
    hipLaunchKernelGGL(k_slices, dim3(256), dim3(256), 0, stream, b22, T, ws);
}